// Round 8
// baseline (11301.077 us; speedup 1.0000x reference)
//
#include <hip/hip_runtime.h>
#include <hip/hip_bf16.h>

#define T_STEPS 2048
#define BATCH   1024
#define NUNITS  128
#define ROWS    2
#define LOG2E   1.4426950408889634f

typedef __attribute__((ext_vector_type(8))) __bf16 bf16x8;
typedef __attribute__((ext_vector_type(4))) float  f32x4;
typedef __attribute__((ext_vector_type(2))) int    i32x2;

__device__ __forceinline__ float sigm_pre(float xs) {
    // xs PRE-SCALED by log2e: sigm = 1/(1+2^-xs)
    return __builtin_amdgcn_rcpf(1.0f + __builtin_amdgcn_exp2f(-xs));
}
__device__ __forceinline__ float tanh_pre(float xs) {
    // xs PRE-SCALED by 2*log2e: tanh = 1 - 2/(1+2^xs); inf-safe (rcp(inf)=0)
    return fmaf(-2.0f, __builtin_amdgcn_rcpf(1.0f + __builtin_amdgcn_exp2f(xs)), 1.0f);
}
// r: lanes 0-31 = a[self], lanes 32-63 = b[lane-32]  (verified R7)
__device__ __forceinline__ float swap_lo(float a, float b) {
    i32x2 r = __builtin_amdgcn_permlane32_swap(__builtin_bit_cast(int, a),
                                               __builtin_bit_cast(int, b),
                                               false, false);
    return __builtin_bit_cast(float, r[0]);
}

// ---------------- embedding pre-pass (HBM-bound, at roof)
__global__ __launch_bounds__(256) void emb_kernel(const float* __restrict__ x,
                                                  const float* __restrict__ Wemb,
                                                  const float* __restrict__ bemb,
                                                  ushort* __restrict__ e_out) {
    int g = blockIdx.x * 256 + threadIdx.x;   // g = t*1024 + b
    int t = g >> 10;
    int b = g & 1023;
    const float* xr = x + ((size_t)b * T_STEPS + t) * 64;

    float4 xv[16];
#pragma unroll
    for (int i = 0; i < 16; i++) xv[i] = ((const float4*)xr)[i];

    float acc[24];
#pragma unroll
    for (int j = 0; j < 24; j++) acc[j] = bemb[j];

#pragma unroll
    for (int d = 0; d < 64; d++) {
        float xs = ((const float*)xv)[d];
#pragma unroll
        for (int j = 0; j < 24; j++) acc[j] = fmaf(xs, Wemb[d * 24 + j], acc[j]);
    }

    uint outp[12];
#pragma unroll
    for (int p = 0; p < 12; p++) {
        float lo = __builtin_amdgcn_rcpf(1.0f + __builtin_amdgcn_exp2f(-LOG2E * acc[2 * p]));
        float hi = __builtin_amdgcn_rcpf(1.0f + __builtin_amdgcn_exp2f(-LOG2E * acc[2 * p + 1]));
        ushort ulo = __builtin_bit_cast(ushort, (__bf16)lo);
        ushort uhi = __builtin_bit_cast(ushort, (__bf16)hi);
        outp[p] = (uint)ulo | ((uint)uhi << 16);
    }
    uint4* dst = (uint4*)(e_out + (size_t)g * 24);
#pragma unroll
    for (int q = 0; q < 3; q++) dst[q] = ((const uint4*)outp)[q];
}

// ---------------- recurrent kernel: 512 blocks x 512 threads (8 waves), 2 rows/block,
// 2 blocks co-resident per CU (launch_bounds(512,4)) so two INDEPENDENT recurrences
// time-share each CU: block B issues while block A sits in its serial
// barrier->ds_read->MFMA->trans chain (R7 post-mortem: chain-bound at ~1600cyc).
// A = z (LDS), B = W (regs): D[m=batchrow][n=unit]; valid rows 0-1 (lanes 0-15,
// regs 0-1). Rows 2-15 of the A-tile read a shared zero row (LDS broadcast).
__global__ __launch_bounds__(512, 4) void lstm_kernel(
    const ushort* __restrict__ e_ws,
    const float* __restrict__ Wf, const float* __restrict__ bf_,
    const float* __restrict__ Wi, const float* __restrict__ bi_,
    const float* __restrict__ Wg, const float* __restrict__ bg_,
    const float* __restrict__ Wo, const float* __restrict__ bo_,
    const float* __restrict__ Wout, const float* __restrict__ bout,
    float* __restrict__ out) {
    __shared__ __align__(16) __bf16 zfrag[2][4][4][16][8];   // [P][ks][kslot][row16][8] = 8 KiB

    const int tid  = threadIdx.x;
    const int lane = tid & 63;
    const int wv   = tid >> 6;      // 0..7 -> unit tile [16wv,16wv+16)
    const int l15  = lane & 15;
    const int kg   = lane >> 4;     // 0..3 (A/B k-group)
    const int r0   = blockIdx.x * ROWS;

    // ---- persistent W fragments wreg[gate][ks] (B operand: n=l15, k=kg*8+j+32ks),
    // pre-scaled by the exp2 constants
    const float* Wp[4] = {Wf, Wi, Wg, Wo};
    const float gsc[4] = {LOG2E, LOG2E, 2.0f * LOG2E, LOG2E};
    const int ucol = wv * 16 + l15;   // this lane's unit (D n-index)
    bf16x8 wreg[4][5];
#pragma unroll
    for (int gt = 0; gt < 4; gt++) {
#pragma unroll
        for (int ks = 0; ks < 5; ks++) {
#pragma unroll
            for (int j = 0; j < 8; j++) {
                int k = ks * 32 + kg * 8 + j;
                float v = 0.0f;
                if (k < 128) v = Wp[gt][(24 + k) * NUNITS + ucol];        // h rows
                else if (k < 152) v = Wp[gt][(k - 128) * NUNITS + ucol];  // e rows
                wreg[gt][ks][j] = (__bf16)(v * gsc[gt]);
            }
        }
    }
    // bias (C of hoisted e-MFMA): cell (m,n) needs bias[unit=n] -> per-lane splat
    const float* Bp[4] = {bf_, bi_, bg_, bo_};
    f32x4 bias[4];
#pragma unroll
    for (int gt = 0; gt < 4; gt++) {
        float bv = Bp[gt][ucol] * gsc[gt];
#pragma unroll
        for (int r = 0; r < 4; r++) bias[gt][r] = bv;
    }
    const f32x4 czero = {0.0f, 0.0f, 0.0f, 0.0f};

    // zero both z buffers (h0 = 0; rows 2-15 stay zero forever)
    for (int i = tid; i < 2 * 4 * 4 * 16 * 8; i += 512) ((__bf16*)zfrag)[i] = (__bf16)0.0f;

    // LDS read base: rows>=2 point at the (never-written) zero row 15 -> same-address
    // broadcast shrinks each ds_read_b128's unique traffic ~8x
    const int row_eff = (l15 < 2) ? l15 : 15;
    const __bf16* zrd = &zfrag[0][0][kg][row_eff][0];
    // write: thread's 1 cell = (row = lane>=32, unit ucol); active lanes 0-15 & 32-47
    const int  row_w = (lane >> 5) & 1;
    const bool wact  = (((lane >> 4) & 1) == 0);
    __bf16* zwr = &zfrag[0][ucol >> 5][(ucol >> 3) & 3][row_w][ucol & 7];

    // ---- e prefetch ring, depth 2 (A rows l15<2, k-groups kg<3)
    const ushort* elbase = e_ws + ((size_t)(r0 + (l15 & 1)) * 24 + kg * 8);
    const bool eload = (kg < 3) && (l15 < 2);
    bf16x8 e0, e1;
#pragma unroll
    for (int j = 0; j < 8; j++) { e0[j] = (__bf16)0.0f; e1[j] = (__bf16)0.0f; }
    if (eload) {
        e0 = *(const bf16x8*)(const void*)(elbase);
        e1 = *(const bf16x8*)(const void*)(elbase + 24576);   // t=1 (1024*24/step)
    }

    __syncthreads();

    float c0 = 0.0f;              // cell state for this thread's single cell
    f32x4 eA[4], eB[4];           // hoisted e-acc (bias + W_e*e(t)) per gate
#pragma unroll
    for (int gt = 0; gt < 4; gt++)
        eA[gt] = __builtin_amdgcn_mfma_f32_16x16x32_bf16(e0, wreg[gt][4], bias[gt], 0, 0, 0);
    if (eload) e0 = *(const bf16x8*)(const void*)(elbase + 2 * 24576);   // e(2)

    auto STEP = [&](int t, int P, f32x4 (&cur)[4], f32x4 (&nxt)[4], bf16x8& enext) {
        const __bf16* zb = zrd + P * 2048;
        bf16x8 z0 = *(const bf16x8*)(const void*)(zb);
        bf16x8 z1 = *(const bf16x8*)(const void*)(zb + 512);
        bf16x8 z2 = *(const bf16x8*)(const void*)(zb + 1024);
        bf16x8 z3 = *(const bf16x8*)(const void*)(zb + 1536);

        // hoisted e-MFMAs for t+1 first (register-only; hides the ds_read latency)
#pragma unroll
        for (int gt = 0; gt < 4; gt++)
            nxt[gt] = __builtin_amdgcn_mfma_f32_16x16x32_bf16(enext, wreg[gt][4], bias[gt], 0, 0, 0);
        {
            int tf = t + 3; if (tf > T_STEPS - 1) tf = T_STEPS - 1;
            if (eload) enext = *(const bf16x8*)(const void*)(elbase + (size_t)tf * 24576);
        }

        // z-MFMAs: two parallel depth-2 chains per gate (halves MFMA chain latency)
        f32x4 ca[4], cb[4];
#pragma unroll
        for (int gt = 0; gt < 4; gt++) {
            ca[gt] = __builtin_amdgcn_mfma_f32_16x16x32_bf16(z0, wreg[gt][0], cur[gt], 0, 0, 0);
            cb[gt] = __builtin_amdgcn_mfma_f32_16x16x32_bf16(z1, wreg[gt][1], czero, 0, 0, 0);
            ca[gt] = __builtin_amdgcn_mfma_f32_16x16x32_bf16(z2, wreg[gt][2], ca[gt], 0, 0, 0);
            cb[gt] = __builtin_amdgcn_mfma_f32_16x16x32_bf16(z3, wreg[gt][3], cb[gt], 0, 0, 0);
        }

        // merge + compact: row0 -> lanes 0-15, row1 -> lanes 32-47 (one swap per gate)
        float g[4];
#pragma unroll
        for (int gt = 0; gt < 4; gt++)
            g[gt] = swap_lo(ca[gt][0] + cb[gt][0], ca[gt][1] + cb[gt][1]);

        float fg = sigm_pre(g[0]);
        float ig = sigm_pre(g[1]);
        float gg = tanh_pre(g[2]);
        float og = sigm_pre(g[3]);
        c0 = fmaf(c0, fg, ig * gg);
        float h = tanh_pre(2.0f * LOG2E * c0) * og;

        if (wact) *(zwr + (P ^ 1) * 2048) = (__bf16)h;

        // LDS-only drain + raw barrier: vmem e-prefetch stays in flight
        asm volatile("s_waitcnt lgkmcnt(0)" ::: "memory");
        __builtin_amdgcn_s_barrier();
        __builtin_amdgcn_sched_barrier(0);
    };

    for (int t = 0; t < T_STEPS; t += 2) {
        STEP(t,     0, eA, eB, e1);
        STEP(t + 1, 1, eB, eA, e0);
    }

    // h_last is in buffer 0 (rows 0-1)
    if (tid < ROWS) {
        float s = bout[0];
#pragma unroll
        for (int k = 0; k < NUNITS; k++)
            s += (float)zfrag[0][k >> 5][(k >> 3) & 3][tid][k & 7] * Wout[k];
        out[r0 + tid] = __builtin_amdgcn_rcpf(1.0f + __builtin_amdgcn_exp2f(-LOG2E * s));
    }
}

extern "C" void kernel_launch(void* const* d_in, const int* in_sizes, int n_in,
                              void* d_out, int out_size, void* d_ws, size_t ws_size,
                              hipStream_t stream) {
    const float* x     = (const float*)d_in[0];
    const float* Wemb  = (const float*)d_in[1];
    const float* bemb  = (const float*)d_in[2];
    const float* Wf    = (const float*)d_in[3];
    const float* bf_   = (const float*)d_in[4];
    const float* Wi    = (const float*)d_in[5];
    const float* bi_   = (const float*)d_in[6];
    const float* Wg    = (const float*)d_in[7];
    const float* bg_   = (const float*)d_in[8];
    const float* Wo    = (const float*)d_in[9];
    const float* bo_   = (const float*)d_in[10];
    const float* Wout  = (const float*)d_in[11];
    const float* bout  = (const float*)d_in[12];
    float* out = (float*)d_out;
    ushort* e_ws = (ushort*)d_ws;   // [T][B][24] bf16, ~96 MB

    int nrows = BATCH * T_STEPS;
    emb_kernel<<<nrows / 256, 256, 0, stream>>>(x, Wemb, bemb, e_ws);
    lstm_kernel<<<BATCH / ROWS, 512, 0, stream>>>(e_ws, Wf, bf_, Wi, bi_, Wg, bg_,
                                                  Wo, bo_, Wout, bout, out);
}

// Round 9
// 2296.231 us; speedup vs baseline: 4.9216x; 4.9216x over previous
//
#include <hip/hip_runtime.h>
#include <hip/hip_bf16.h>

#define T_STEPS 2048
#define BATCH   1024
#define NUNITS  128
#define ROWS    2
#define LOG2E   1.4426950408889634f

typedef __attribute__((ext_vector_type(8))) __bf16 bf16x8;
typedef __attribute__((ext_vector_type(4))) float  f32x4;
typedef __attribute__((ext_vector_type(2))) int    i32x2;

__device__ __forceinline__ float sigm_pre(float xs) {
    // xs PRE-SCALED by log2e: sigm = 1/(1+2^-xs)
    return __builtin_amdgcn_rcpf(1.0f + __builtin_amdgcn_exp2f(-xs));
}
__device__ __forceinline__ float tanh_pre(float xs) {
    // xs PRE-SCALED by 2*log2e: tanh = 1 - 2/(1+2^xs); inf-safe (rcp(inf)=0)
    return fmaf(-2.0f, __builtin_amdgcn_rcpf(1.0f + __builtin_amdgcn_exp2f(xs)), 1.0f);
}
// r: lanes 0-31 = a[self], lanes 32-63 = b[lane-32]  (verified R7)
__device__ __forceinline__ float swap_lo(float a, float b) {
    i32x2 r = __builtin_amdgcn_permlane32_swap(__builtin_bit_cast(int, a),
                                               __builtin_bit_cast(int, b),
                                               false, false);
    return __builtin_bit_cast(float, r[0]);
}

// ---------------- embedding pre-pass (HBM-bound, at roof)
__global__ __launch_bounds__(256) void emb_kernel(const float* __restrict__ x,
                                                  const float* __restrict__ Wemb,
                                                  const float* __restrict__ bemb,
                                                  ushort* __restrict__ e_out) {
    int g = blockIdx.x * 256 + threadIdx.x;   // g = t*1024 + b
    int t = g >> 10;
    int b = g & 1023;
    const float* xr = x + ((size_t)b * T_STEPS + t) * 64;

    float4 xv[16];
#pragma unroll
    for (int i = 0; i < 16; i++) xv[i] = ((const float4*)xr)[i];

    float acc[24];
#pragma unroll
    for (int j = 0; j < 24; j++) acc[j] = bemb[j];

#pragma unroll
    for (int d = 0; d < 64; d++) {
        float xs = ((const float*)xv)[d];
#pragma unroll
        for (int j = 0; j < 24; j++) acc[j] = fmaf(xs, Wemb[d * 24 + j], acc[j]);
    }

    uint outp[12];
#pragma unroll
    for (int p = 0; p < 12; p++) {
        float lo = __builtin_amdgcn_rcpf(1.0f + __builtin_amdgcn_exp2f(-LOG2E * acc[2 * p]));
        float hi = __builtin_amdgcn_rcpf(1.0f + __builtin_amdgcn_exp2f(-LOG2E * acc[2 * p + 1]));
        ushort ulo = __builtin_bit_cast(ushort, (__bf16)lo);
        ushort uhi = __builtin_bit_cast(ushort, (__bf16)hi);
        outp[p] = (uint)ulo | ((uint)uhi << 16);
    }
    uint4* dst = (uint4*)(e_out + (size_t)g * 24);
#pragma unroll
    for (int q = 0; q < 3; q++) dst[q] = ((const uint4*)outp)[q];
}

// ---------------- recurrent kernel: 512 blocks x 512 threads (8 waves), 2 rows/block,
// 2 blocks co-resident per CU so two INDEPENDENT recurrences time-share each CU.
// R8 post-mortem: __launch_bounds__(512,4) capped VGPR at 64 -> wreg spilled to
// scratch -> 38 GB/dispatch refetch. (512,2) gives a 128-VGPR budget (kernel needs
// ~104) while still fitting 2 blocks/CU (16 waves/CU at <=128 VGPR).
// A = z (LDS), B = W (regs): D[m=batchrow][n=unit]; valid rows 0-1 (lanes 0-15,
// regs 0-1). Rows 2-15 of the A-tile read a shared zero row (LDS broadcast).
__global__ __launch_bounds__(512, 2) void lstm_kernel(
    const ushort* __restrict__ e_ws,
    const float* __restrict__ Wf, const float* __restrict__ bf_,
    const float* __restrict__ Wi, const float* __restrict__ bi_,
    const float* __restrict__ Wg, const float* __restrict__ bg_,
    const float* __restrict__ Wo, const float* __restrict__ bo_,
    const float* __restrict__ Wout, const float* __restrict__ bout,
    float* __restrict__ out) {
    __shared__ __align__(16) __bf16 zfrag[2][4][4][16][8];   // [P][ks][kslot][row16][8] = 8 KiB

    const int tid  = threadIdx.x;
    const int lane = tid & 63;
    const int wv   = tid >> 6;      // 0..7 -> unit tile [16wv,16wv+16)
    const int l15  = lane & 15;
    const int kg   = lane >> 4;     // 0..3 (A/B k-group)
    const int r0   = blockIdx.x * ROWS;

    // ---- persistent W fragments wreg[gate][ks] (B operand: n=l15, k=kg*8+j+32ks),
    // pre-scaled by the exp2 constants
    const float* Wp[4] = {Wf, Wi, Wg, Wo};
    const float gsc[4] = {LOG2E, LOG2E, 2.0f * LOG2E, LOG2E};
    const int ucol = wv * 16 + l15;   // this lane's unit (D n-index)
    bf16x8 wreg[4][5];
#pragma unroll
    for (int gt = 0; gt < 4; gt++) {
#pragma unroll
        for (int ks = 0; ks < 5; ks++) {
#pragma unroll
            for (int j = 0; j < 8; j++) {
                int k = ks * 32 + kg * 8 + j;
                float v = 0.0f;
                if (k < 128) v = Wp[gt][(24 + k) * NUNITS + ucol];        // h rows
                else if (k < 152) v = Wp[gt][(k - 128) * NUNITS + ucol];  // e rows
                wreg[gt][ks][j] = (__bf16)(v * gsc[gt]);
            }
        }
    }
    // bias (C of hoisted e-MFMA): cell (m,n) needs bias[unit=n] -> per-lane splat
    const float* Bp[4] = {bf_, bi_, bg_, bo_};
    f32x4 bias[4];
#pragma unroll
    for (int gt = 0; gt < 4; gt++) {
        float bv = Bp[gt][ucol] * gsc[gt];
#pragma unroll
        for (int r = 0; r < 4; r++) bias[gt][r] = bv;
    }
    const f32x4 czero = {0.0f, 0.0f, 0.0f, 0.0f};

    // zero both z buffers (h0 = 0; rows 2-15 stay zero forever)
    for (int i = tid; i < 2 * 4 * 4 * 16 * 8; i += 512) ((__bf16*)zfrag)[i] = (__bf16)0.0f;

    // LDS read base: rows>=2 point at the (never-written) zero row 15 -> same-address
    // broadcast shrinks each ds_read_b128's unique traffic ~8x
    const int row_eff = (l15 < 2) ? l15 : 15;
    const __bf16* zrd = &zfrag[0][0][kg][row_eff][0];
    // write: thread's 1 cell = (row = lane>=32, unit ucol); active lanes 0-15 & 32-47
    const int  row_w = (lane >> 5) & 1;
    const bool wact  = (((lane >> 4) & 1) == 0);
    __bf16* zwr = &zfrag[0][ucol >> 5][(ucol >> 3) & 3][row_w][ucol & 7];

    // ---- e prefetch ring, depth 2 (A rows l15<2, k-groups kg<3)
    const ushort* elbase = e_ws + ((size_t)(r0 + (l15 & 1)) * 24 + kg * 8);
    const bool eload = (kg < 3) && (l15 < 2);
    bf16x8 e0, e1;
#pragma unroll
    for (int j = 0; j < 8; j++) { e0[j] = (__bf16)0.0f; e1[j] = (__bf16)0.0f; }
    if (eload) {
        e0 = *(const bf16x8*)(const void*)(elbase);
        e1 = *(const bf16x8*)(const void*)(elbase + 24576);   // t=1 (1024*24/step)
    }

    __syncthreads();

    float c0 = 0.0f;              // cell state for this thread's single cell
    f32x4 eA[4], eB[4];           // hoisted e-acc (bias + W_e*e(t)) per gate
#pragma unroll
    for (int gt = 0; gt < 4; gt++)
        eA[gt] = __builtin_amdgcn_mfma_f32_16x16x32_bf16(e0, wreg[gt][4], bias[gt], 0, 0, 0);
    if (eload) e0 = *(const bf16x8*)(const void*)(elbase + 2 * 24576);   // e(2)

    auto STEP = [&](int t, int P, f32x4 (&cur)[4], f32x4 (&nxt)[4], bf16x8& enext) {
        const __bf16* zb = zrd + P * 2048;
        bf16x8 z0 = *(const bf16x8*)(const void*)(zb);
        bf16x8 z1 = *(const bf16x8*)(const void*)(zb + 512);
        bf16x8 z2 = *(const bf16x8*)(const void*)(zb + 1024);
        bf16x8 z3 = *(const bf16x8*)(const void*)(zb + 1536);

        // hoisted e-MFMAs for t+1 first (register-only; hides the ds_read latency)
#pragma unroll
        for (int gt = 0; gt < 4; gt++)
            nxt[gt] = __builtin_amdgcn_mfma_f32_16x16x32_bf16(enext, wreg[gt][4], bias[gt], 0, 0, 0);
        {
            int tf = t + 3; if (tf > T_STEPS - 1) tf = T_STEPS - 1;
            if (eload) enext = *(const bf16x8*)(const void*)(elbase + (size_t)tf * 24576);
        }

        // z-MFMAs: two parallel depth-2 chains per gate (halves MFMA chain latency)
        f32x4 ca[4], cb[4];
#pragma unroll
        for (int gt = 0; gt < 4; gt++) {
            ca[gt] = __builtin_amdgcn_mfma_f32_16x16x32_bf16(z0, wreg[gt][0], cur[gt], 0, 0, 0);
            cb[gt] = __builtin_amdgcn_mfma_f32_16x16x32_bf16(z1, wreg[gt][1], czero, 0, 0, 0);
            ca[gt] = __builtin_amdgcn_mfma_f32_16x16x32_bf16(z2, wreg[gt][2], ca[gt], 0, 0, 0);
            cb[gt] = __builtin_amdgcn_mfma_f32_16x16x32_bf16(z3, wreg[gt][3], cb[gt], 0, 0, 0);
        }

        // merge + compact: row0 -> lanes 0-15, row1 -> lanes 32-47 (one swap per gate)
        float g[4];
#pragma unroll
        for (int gt = 0; gt < 4; gt++)
            g[gt] = swap_lo(ca[gt][0] + cb[gt][0], ca[gt][1] + cb[gt][1]);

        float fg = sigm_pre(g[0]);
        float ig = sigm_pre(g[1]);
        float gg = tanh_pre(g[2]);
        float og = sigm_pre(g[3]);
        c0 = fmaf(c0, fg, ig * gg);
        float h = tanh_pre(2.0f * LOG2E * c0) * og;

        if (wact) *(zwr + (P ^ 1) * 2048) = (__bf16)h;

        // LDS-only drain + raw barrier: vmem e-prefetch stays in flight
        asm volatile("s_waitcnt lgkmcnt(0)" ::: "memory");
        __builtin_amdgcn_s_barrier();
        __builtin_amdgcn_sched_barrier(0);
    };

    for (int t = 0; t < T_STEPS; t += 2) {
        STEP(t,     0, eA, eB, e1);
        STEP(t + 1, 1, eB, eA, e0);
    }

    // h_last is in buffer 0 (rows 0-1)
    if (tid < ROWS) {
        float s = bout[0];
#pragma unroll
        for (int k = 0; k < NUNITS; k++)
            s += (float)zfrag[0][k >> 5][(k >> 3) & 3][tid][k & 7] * Wout[k];
        out[r0 + tid] = __builtin_amdgcn_rcpf(1.0f + __builtin_amdgcn_exp2f(-LOG2E * s));
    }
}

extern "C" void kernel_launch(void* const* d_in, const int* in_sizes, int n_in,
                              void* d_out, int out_size, void* d_ws, size_t ws_size,
                              hipStream_t stream) {
    const float* x     = (const float*)d_in[0];
    const float* Wemb  = (const float*)d_in[1];
    const float* bemb  = (const float*)d_in[2];
    const float* Wf    = (const float*)d_in[3];
    const float* bf_   = (const float*)d_in[4];
    const float* Wi    = (const float*)d_in[5];
    const float* bi_   = (const float*)d_in[6];
    const float* Wg    = (const float*)d_in[7];
    const float* bg_   = (const float*)d_in[8];
    const float* Wo    = (const float*)d_in[9];
    const float* bo_   = (const float*)d_in[10];
    const float* Wout  = (const float*)d_in[11];
    const float* bout  = (const float*)d_in[12];
    float* out = (float*)d_out;
    ushort* e_ws = (ushort*)d_ws;   // [T][B][24] bf16, ~96 MB

    int nrows = BATCH * T_STEPS;
    emb_kernel<<<nrows / 256, 256, 0, stream>>>(x, Wemb, bemb, e_ws);
    lstm_kernel<<<BATCH / ROWS, 512, 0, stream>>>(e_ws, Wf, bf_, Wi, bi_, Wg, bg_,
                                                  Wo, bo_, Wout, bout, out);
}